// Round 3
// baseline (439.336 us; speedup 1.0000x reference)
//
#include <hip/hip_runtime.h>

#define NROW 6
#define NCOL 6
#define BATCH 1024

// One block = one sample. Exact 6x6 PEPS (D=4, open boundary) contracted by
// row-major single-site absorption. The inter-step intermediate (up to 4^7
// elements) lives in REGISTERS: thread t holds, for each (g', z, s), the
// element whose spectator index m = t + 256*s. Each step streams the previous
// state through LDS one g-slice at a time (<= 4096 floats), double-buffered
// with globally alternating parity (one barrier per slice is then race-free:
// reads of buffer P finish before the barrier that precedes the next write to
// P, two slice-iterations later). Peak LDS = 32 KB (well under any limit).
// The 16x16 site matrix M[(g',z)][(g,x)] = T[u=x][r=g'][d=z][l=g] is held in
// wave registers (lane (g'*4+z)*4+g holds the 4 x-values) and broadcast with
// constant-lane __shfl (v_readlane). Dangling bonds = index 0, matching the
// reference's isel: top row xs=1, bottom row z=0 only, left col g=0, right
// col g'=0.
__global__ void peps_amp_kernel(const int* __restrict__ X,
                                const float* __restrict__ Tg,
                                float* __restrict__ out)
{
    __shared__ float buf[2][4096];        // 32 KB total

    const int b    = blockIdx.x;
    const int t    = threadIdx.x;
    const int lane = t & 63;
    const int mrow = lane >> 2;           // g' = mrow>>2, z = mrow&3
    const int mq   = lane & 3;            // g
    // T site axes (u,r,d,l) strides (64,16,4,1)
    const int moff = (mrow >> 2) * 16 + (mrow & 3) * 4 + mq;
    const int* xrow = X + b * (NROW * NCOL);

    // M for step 0
    float m4[4];
    {
        const int spin = xrow[0];
        const float* Ts = Tg + (size_t)spin * 256;
        #pragma unroll
        for (int x = 0; x < 4; ++x) m4[x] = Ts[x * 64 + moff];
    }

    float r[4][4][4];                     // state [g'][z][s]
    int pm_count = 1;                     // prev step's spectator count
    int pz4 = 0;                          // prev step's zs==4 ?
    int pb = 0;                           // LDS slice parity (uniform)
    int step = 0;

    for (int row = 0; row < NROW; ++row) {
        const int xs = (row == 0) ? 1 : 4;          // up bond (top edge -> 1)
        const int zs = (row == NROW - 1) ? 1 : 4;   // down bond (bottom edge -> 1)
        for (int c = 0; c < NCOL; ++c, ++step) {
            const int gin   = (c == 0) ? 1 : 4;     // left bond (left edge -> 1)
            const int mbits = ((xs == 4) ? 2 * (5 - c) : 0) + ((zs == 4) ? 2 * c : 0);
            const int mcount = 1 << mbits;          // spectators this step

            // prefetch next step's M (L2-resident; hidden under compute)
            float m4n[4] = {0.f, 0.f, 0.f, 0.f};
            if (step + 1 < NROW * NCOL) {
                const int spin = xrow[step + 1];
                const float* Ts = Tg + (size_t)((step + 1) * 2 + spin) * 256;
                #pragma unroll
                for (int x = 0; x < 4; ++x) m4n[x] = Ts[x * 64 + moff];
            }

            float acc[4][4][4];                     // next state [g'][z][s]
            #pragma unroll
            for (int gp = 0; gp < 4; ++gp)
                #pragma unroll
                for (int z = 0; z < 4; ++z)
                    #pragma unroll
                    for (int s = 0; s < 4; ++s) acc[gp][z][s] = 0.f;

            #pragma unroll
            for (int g = 0; g < 4; ++g) {
                if (g < gin) {                      // uniform guard; r[g] index stays constant
                    float* sb = buf[pb]; pb ^= 1;
                    // ---- stage slice g of the previous state ----
                    if (step == 0) {
                        if (t == 0) sb[0] = 1.0f;   // scalar seed
                    } else {
                        #pragma unroll
                        for (int s = 0; s < 4; ++s) {
                            const int mp = t + 256 * s;
                            if (mp < pm_count) {
                                if (pz4) {
                                    *(float4*)&sb[mp << 2] = make_float4(
                                        r[g][0][s], r[g][1][s], r[g][2][s], r[g][3][s]);
                                } else {
                                    sb[mp] = r[g][0][s];
                                }
                            }
                        }
                    }
                    __syncthreads();
                    // ---- read slice + accumulate ----
                    #pragma unroll
                    for (int x = 0; x < 4; ++x) {
                        if (x < xs) {               // uniform guard
                            float wv[4];
                            #pragma unroll
                            for (int s = 0; s < 4; ++s) {
                                const int m = t + 256 * s;
                                wv[s] = (m < mcount) ? sb[(x << mbits) + m] : 0.f;
                            }
                            #pragma unroll
                            for (int gp = 0; gp < 4; ++gp)
                                #pragma unroll
                                for (int z = 0; z < 4; ++z) {
                                    const float mv =
                                        __shfl(m4[x], (((gp << 2) | z) << 2) | g, 64);
                                    #pragma unroll
                                    for (int s = 0; s < 4; ++s)
                                        acc[gp][z][s] += mv * wv[s];
                                }
                        }
                    }
                }
            }

            // ---- commit ----
            #pragma unroll
            for (int gp = 0; gp < 4; ++gp)
                #pragma unroll
                for (int z = 0; z < 4; ++z)
                    #pragma unroll
                    for (int s = 0; s < 4; ++s) r[gp][z][s] = acc[gp][z][s];
            #pragma unroll
            for (int x = 0; x < 4; ++x) m4[x] = m4n[x];
            pm_count = mcount;
            pz4 = (zs == 4) ? 1 : 0;
        }
    }
    // after (5,5): only g'=0, z=0, m=0 valid -> thread 0, s=0
    if (t == 0) out[b] = r[0][0][0];
}

extern "C" void kernel_launch(void* const* d_in, const int* in_sizes, int n_in,
                              void* d_out, int out_size, void* d_ws, size_t ws_size,
                              hipStream_t stream) {
    const int*   X  = (const int*)d_in[0];     // x: [1024, 36] int32
    const float* Tg = (const float*)d_in[1];   // T: [6,6,2,4,4,4,4] fp32
    float* out = (float*)d_out;                // reference output dtype: float32
    (void)in_sizes; (void)n_in; (void)d_ws; (void)ws_size; (void)out_size;
    peps_amp_kernel<<<dim3(BATCH), dim3(256), 0, stream>>>(X, Tg, out);
}